// Round 7
// baseline (610.990 us; speedup 1.0000x reference)
//
#include <hip/hip_runtime.h>
#include <math.h>

#define N_NODES 50000
#define N_EDGES 400000
#define N_TRAIN 50000
#define IN_DIM  128
#define HIDDEN  512
#define M_PAD   50176   // 196 * 256

typedef _Float16 f16;
typedef __attribute__((ext_vector_type(8))) _Float16 f16x8;
typedef __attribute__((ext_vector_type(4))) _Float16 f16x4;
typedef __attribute__((ext_vector_type(4))) float f32x4;

// ---------------- graph preprocessing ----------------

__global__ void count_dst_kernel(const int* __restrict__ dst, int* __restrict__ cnt) {
    int i = blockIdx.x * blockDim.x + threadIdx.x;
    if (i < N_EDGES) atomicAdd(&cnt[dst[i]], 1);
}

__global__ void dis_kernel(const int* __restrict__ cnt, float* __restrict__ dis) {
    int v = blockIdx.x * blockDim.x + threadIdx.x;
    if (v < N_NODES) dis[v] = rsqrtf(1.0f + (float)cnt[v]);  // +1 self-loop
}

__global__ void scan_kernel(const int* __restrict__ cnt, int* __restrict__ off) {
    __shared__ int part[1024];
    const int T = 1024;
    const int chunk = (N_NODES + T - 1) / T;
    int t = threadIdx.x;
    int s = t * chunk, e = min(s + chunk, N_NODES);
    int sum = 0;
    for (int i = s; i < e; i++) sum += cnt[i];
    part[t] = sum;
    __syncthreads();
    for (int o = 1; o < T; o <<= 1) {
        int v = (t >= o) ? part[t - o] : 0;
        __syncthreads();
        part[t] += v;
        __syncthreads();
    }
    int run = part[t] - sum;
    for (int i = s; i < e; i++) { off[i] = run; run += cnt[i]; }
    if (t == T - 1) off[N_NODES] = run;
}

__global__ void fill_csr_kernel(const int* __restrict__ src, const int* __restrict__ dst,
                                const int* __restrict__ off, int* __restrict__ cursor,
                                int* __restrict__ csr_src) {
    int i = blockIdx.x * blockDim.x + threadIdx.x;
    if (i < N_EDGES) {
        int d = dst[i];
        int p = atomicAdd(&cursor[d], 1);
        csr_src[off[d] + p] = src[i];
    }
}

// ------------- weight conversion: W[K][512] -> Bt[512][2K] = [hi | lo] rows -------------
__global__ void convw_kernel(const float* __restrict__ W, f16* __restrict__ Bt, int K) {
    int idx = blockIdx.x * blockDim.x + threadIdx.x;
    if (idx >= K * HIDDEN) return;
    int k = idx / HIDDEN, n = idx % HIDDEN;
    float w = W[(size_t)k * HIDDEN + n];
    f16 hi = (f16)w;
    f16 lo = (f16)(w - (float)hi);
    size_t base = (size_t)n * 2 * K;
    Bt[base + k]     = hi;
    Bt[base + K + k] = lo;
}

// ------------- layer-1 aggregation: f32 x (D=128) -> fp16 (stride 128) -------------
__global__ void agg1_kernel(const float* __restrict__ x, const float* __restrict__ dis,
                            const int* __restrict__ off, const int* __restrict__ csr_src,
                            f16* __restrict__ A) {
    const int TPN = 32;   // 128/4
    int node = blockIdx.x * 8 + threadIdx.x / TPN;
    if (node >= N_NODES) return;
    int t = threadIdx.x % TPN;
    float dv = dis[node];
    float w0 = dv * dv;
    float4 a = ((const float4*)(x + (size_t)node * IN_DIM))[t];
    float4 acc = make_float4(a.x * w0, a.y * w0, a.z * w0, a.w * w0);
    int s0 = off[node], s1 = off[node + 1];
    for (int k = s0; k < s1; k++) {
        int s = csr_src[k];
        float w = dis[s] * dv;
        float4 b = ((const float4*)(x + (size_t)s * IN_DIM))[t];
        acc.x = fmaf(w, b.x, acc.x);
        acc.y = fmaf(w, b.y, acc.y);
        acc.z = fmaf(w, b.z, acc.z);
        acc.w = fmaf(w, b.w, acc.w);
    }
    f16x4 o;
    o.x = (f16)acc.x; o.y = (f16)acc.y; o.z = (f16)acc.z; o.w = (f16)acc.w;
    *(f16x4*)&A[(size_t)node * IN_DIM + t * 4] = o;
}

// ------------- aggregation: fp16 h (512) -> fp16 (stride 512), 2-way unrolled -------------
__global__ void agg_f16_kernel(const f16* __restrict__ h, const float* __restrict__ dis,
                               const int* __restrict__ off, const int* __restrict__ csr_src,
                               f16* __restrict__ A) {
    const int TPN = 64;   // 512/8, one wave per node
    int node = blockIdx.x * 4 + threadIdx.x / TPN;
    if (node >= N_NODES) return;
    int t = threadIdx.x % TPN;
    float dv = dis[node];
    float w0 = dv * dv;
    f16x8 a = *(const f16x8*)&h[(size_t)node * HIDDEN + t * 8];
    float acc0[8], acc1[8];
    #pragma unroll
    for (int j = 0; j < 8; j++) { acc0[j] = w0 * (float)a[j]; acc1[j] = 0.f; }
    int s0 = off[node], s1 = off[node + 1];
    int k = s0;
    for (; k + 2 <= s1; k += 2) {      // two independent gathers in flight
        int sa = csr_src[k], sb = csr_src[k + 1];
        float wa = dis[sa] * dv, wb = dis[sb] * dv;
        f16x8 ba = *(const f16x8*)&h[(size_t)sa * HIDDEN + t * 8];
        f16x8 bb = *(const f16x8*)&h[(size_t)sb * HIDDEN + t * 8];
        #pragma unroll
        for (int j = 0; j < 8; j++) acc0[j] = fmaf(wa, (float)ba[j], acc0[j]);
        #pragma unroll
        for (int j = 0; j < 8; j++) acc1[j] = fmaf(wb, (float)bb[j], acc1[j]);
    }
    if (k < s1) {
        int sa = csr_src[k];
        float wa = dis[sa] * dv;
        f16x8 ba = *(const f16x8*)&h[(size_t)sa * HIDDEN + t * 8];
        #pragma unroll
        for (int j = 0; j < 8; j++) acc0[j] = fmaf(wa, (float)ba[j], acc0[j]);
    }
    f16x8 o;
    #pragma unroll
    for (int j = 0; j < 8; j++) o[j] = (f16)(acc0[j] + acc1[j]);
    *(f16x8*)&A[(size_t)node * HIDDEN + t * 8] = o;
}

// ------- MFMA fp16 GEMM, hi/lo-fused, counted-vmcnt pipeline (T3+T4) -------
// C[M][512] = tanh(A @ (B_hi + B_lo) + bias).  256x128 tile, 8 waves, BK=64.
// 2-deep prefetch: stage(t) completion is awaited with s_waitcnt vmcnt(8)
// (stage(t+1)'s 8 loads stay IN FLIGHT across the raw s_barrier — never drain
// to 0 in the main loop, per T4/m218). Each wave: vmcnt(8) -> barrier ->
// ds_read+MFMA -> barrier -> stage(t+2) into the buffer just consumed.
// XOR-swizzle per rule #21 (linear LDS dest + inverse-swizzled global src + swizzled read).
__global__ __launch_bounds__(512, 2) void gemm_mfma_kernel(
    const f16* __restrict__ A, const f16* __restrict__ Bt, const float* __restrict__ bias,
    f16* __restrict__ C, int M, int Kb) {
    __shared__ f16 As[2][256 * 64];      // 64 KB
    __shared__ f16 Bs[2][2][128 * 64];   // 64 KB  [buf][hi/lo][col][k]
    const int Kp = 2 * Kb;
    int tid = threadIdx.x;
    int lane = tid & 63, wv = tid >> 6;
    int wr = wv >> 2, wc = wv & 3;       // 2 M-halves x 4 N-quarters

    // bijective XCD swizzle (m204); grid 784 = 98*8
    int nwg = gridDim.x;
    int q = nwg >> 3, r = nwg & 7;
    int xcd = blockIdx.x & 7, pos = blockIdx.x >> 3;
    int wgid = (xcd < r ? xcd * (q + 1) : r * (q + 1) + (xcd - r) * q) + pos;
    int j0 = (wgid & 3) * 128;           // 4 col tiles
    int i0 = (wgid >> 2) * 256;          // 196 row tiles

    int l15 = lane & 15, l4 = lane >> 4;

    f32x4 acc[8][2];
    #pragma unroll
    for (int m = 0; m < 8; m++)
        #pragma unroll
        for (int n = 0; n < 2; n++)
            acc[m][n] = (f32x4){0.f, 0.f, 0.f, 0.f};

    const int nt = Kb / 64;

    auto stage = [&](int t, int buf) {
        int k0 = t * 64;
        #pragma unroll
        for (int i = 0; i < 4; i++) {            // A: 256x64 = 2048 slots (4 VMEM/thread)
            int s = i * 512 + tid;
            int row = s >> 3, c8 = s & 7;
            int c8s = c8 ^ (row & 7);            // inverse-swizzled source column
            const f16* gp = A + (size_t)(i0 + row) * Kb + k0 + c8s * 8;
            f16* lp = &As[buf][(i * 512 + wv * 64) * 8];   // wave-uniform base
            __builtin_amdgcn_global_load_lds(
                (const __attribute__((address_space(1))) void*)gp,
                (__attribute__((address_space(3))) void*)lp, 16, 0, 0);
        }
        #pragma unroll
        for (int v = 0; v < 2; v++) {            // B hi/lo: 128x64 each (4 VMEM/thread total)
            #pragma unroll
            for (int i = 0; i < 2; i++) {
                int s = i * 512 + tid;
                int row = s >> 3, c8 = s & 7;
                int c8s = c8 ^ (row & 7);
                const f16* gp = Bt + (size_t)(j0 + row) * Kp + v * Kb + k0 + c8s * 8;
                f16* lp = &Bs[buf][v][(i * 512 + wv * 64) * 8];
                __builtin_amdgcn_global_load_lds(
                    (const __attribute__((address_space(1))) void*)gp,
                    (__attribute__((address_space(3))) void*)lp, 16, 0, 0);
            }
        }
    };

    // prologue: two tiles in flight (16 VMEM/thread outstanding)
    stage(0, 0);
    if (nt > 1) stage(1, 1);

    for (int t = 0; t < nt; t++) {
        int cur = t & 1;
        // wait for stage(t) only; stage(t+1)'s 8 loads stay in flight across the barrier
        if (t + 1 < nt) asm volatile("s_waitcnt vmcnt(8)" ::: "memory");
        else            asm volatile("s_waitcnt vmcnt(0)" ::: "memory");
        __builtin_amdgcn_s_barrier();            // all waves' DMA for tile t visible
        __builtin_amdgcn_sched_barrier(0);       // fence: no ds_read hoists above (rule #18)

        f16x8 af[8][2], bfr[2][2][2];
        #pragma unroll
        for (int m = 0; m < 8; m++) {
            int row = wr * 128 + m * 16 + l15;
            #pragma unroll
            for (int kk = 0; kk < 2; kk++) {
                int slot = (kk * 4 + l4) ^ (row & 7);
                af[m][kk] = *(const f16x8*)&As[cur][row * 64 + slot * 8];
            }
        }
        #pragma unroll
        for (int n = 0; n < 2; n++) {
            int brow = wc * 32 + n * 16 + l15;
            #pragma unroll
            for (int v = 0; v < 2; v++)
                #pragma unroll
                for (int kk = 0; kk < 2; kk++) {
                    int slot = (kk * 4 + l4) ^ (brow & 7);
                    bfr[n][v][kk] = *(const f16x8*)&Bs[cur][v][brow * 64 + slot * 8];
                }
        }
        __builtin_amdgcn_s_setprio(1);
        #pragma unroll
        for (int m = 0; m < 8; m++)
            #pragma unroll
            for (int n = 0; n < 2; n++)
                #pragma unroll
                for (int v = 0; v < 2; v++)
                    #pragma unroll
                    for (int kk = 0; kk < 2; kk++)
                        acc[m][n] = __builtin_amdgcn_mfma_f32_16x16x32_f16(
                            af[m][kk], bfr[n][v][kk], acc[m][n], 0, 0, 0);
        __builtin_amdgcn_s_setprio(0);
        __builtin_amdgcn_sched_barrier(0);       // keep reads/MFMA above the barrier
        __builtin_amdgcn_s_barrier();            // all waves done reading buf[cur]
        if (t + 2 < nt) stage(t + 2, cur);       // overwrite consumed buffer
    }

    #pragma unroll
    for (int m = 0; m < 8; m++) {
        #pragma unroll
        for (int n = 0; n < 2; n++) {
            int col = j0 + wc * 32 + n * 16 + l15;
            float bc = bias[col];
            #pragma unroll
            for (int r = 0; r < 4; r++) {
                int row = i0 + wr * 128 + m * 16 + l4 * 4 + r;
                if (row < M)
                    C[(size_t)row * HIDDEN + col] = (f16)tanhf(acc[m][n][r] + bc);
            }
        }
    }
}

// ---------------- final edge scoring (fp16 input) ----------------
__global__ void edge_score_kernel(const f16* __restrict__ h,
                                  const int* __restrict__ src, const int* __restrict__ dst,
                                  const int* __restrict__ te, const float* __restrict__ wgt,
                                  const float* __restrict__ fc2b, float* __restrict__ out) {
    int wid = threadIdx.x / 64;
    int lane = threadIdx.x % 64;
    int e = blockIdx.x * 4 + wid;
    if (e >= N_TRAIN) return;
    int id = te[e];
    int a = src[id], b = dst[id];
    f16x8 ha = *(const f16x8*)&h[(size_t)a * HIDDEN + lane * 8];
    f16x8 hb = *(const f16x8*)&h[(size_t)b * HIDDEN + lane * 8];
    float4 w0 = *(const float4*)&wgt[lane * 8];
    float4 w1 = *(const float4*)&wgt[lane * 8 + 4];
    float acc = 0.f;
    acc += (float)ha[0] * (float)hb[0] * w0.x;
    acc += (float)ha[1] * (float)hb[1] * w0.y;
    acc += (float)ha[2] * (float)hb[2] * w0.z;
    acc += (float)ha[3] * (float)hb[3] * w0.w;
    acc += (float)ha[4] * (float)hb[4] * w1.x;
    acc += (float)ha[5] * (float)hb[5] * w1.y;
    acc += (float)ha[6] * (float)hb[6] * w1.z;
    acc += (float)ha[7] * (float)hb[7] * w1.w;
    #pragma unroll
    for (int o = 32; o > 0; o >>= 1) acc += __shfl_down(acc, o);
    if (lane == 0) out[e] = acc + fc2b[0];
}

// ---------------- launch ----------------

extern "C" void kernel_launch(void* const* d_in, const int* in_sizes, int n_in,
                              void* d_out, int out_size, void* d_ws, size_t ws_size,
                              hipStream_t stream) {
    const float* x    = (const float*)d_in[0];
    const int*   eidx = (const int*)d_in[1];
    const int*   te   = (const int*)d_in[2];
    const float* W1   = (const float*)d_in[3];
    const float* b1   = (const float*)d_in[4];
    const float* W2   = (const float*)d_in[5];
    const float* b2   = (const float*)d_in[6];
    const float* W3   = (const float*)d_in[7];
    const float* b3   = (const float*)d_in[8];
    const float* fc2W = (const float*)d_in[9];
    const float* fc2b = (const float*)d_in[10];
    const int* srcp = eidx;
    const int* dstp = eidx + N_EDGES;

    char* ws = (char*)d_ws;
    size_t used = 0;
    auto alloc = [&](size_t bytes) {
        void* p = ws + used;
        used += (bytes + 255) / 256 * 256;
        return p;
    };
    int*   cnt     = (int*)alloc((size_t)N_NODES * 4);
    int*   off     = (int*)alloc((size_t)(N_NODES + 1) * 4);
    int*   cursor  = (int*)alloc((size_t)N_NODES * 4);
    int*   csr_src = (int*)alloc((size_t)N_EDGES * 4);
    float* dis     = (float*)alloc((size_t)N_NODES * 4);
    f16* Bt1 = (f16*)alloc((size_t)HIDDEN * 2 * IN_DIM * 2);
    f16* Bt2 = (f16*)alloc((size_t)HIDDEN * 2 * HIDDEN * 2);
    f16* Bt3 = (f16*)alloc((size_t)HIDDEN * 2 * HIDDEN * 2);
    f16* GA  = (f16*)alloc((size_t)M_PAD * HIDDEN * 2);   // GEMM A operand
    f16* F   = (f16*)alloc((size_t)M_PAD * HIDDEN * 2);   // layer output

    if (used > ws_size) return;  // fail cleanly rather than OOB

    hipMemsetAsync(cnt, 0, (size_t)N_NODES * 4, stream);
    hipMemsetAsync(cursor, 0, (size_t)N_NODES * 4, stream);

    count_dst_kernel<<<(N_EDGES + 255) / 256, 256, 0, stream>>>(dstp, cnt);
    dis_kernel<<<(N_NODES + 255) / 256, 256, 0, stream>>>(cnt, dis);
    scan_kernel<<<1, 1024, 0, stream>>>(cnt, off);
    fill_csr_kernel<<<(N_EDGES + 255) / 256, 256, 0, stream>>>(srcp, dstp, off, cursor, csr_src);

    convw_kernel<<<(IN_DIM * HIDDEN + 255) / 256, 256, 0, stream>>>(W1, Bt1, IN_DIM);
    convw_kernel<<<(HIDDEN * HIDDEN + 255) / 256, 256, 0, stream>>>(W2, Bt2, HIDDEN);
    convw_kernel<<<(HIDDEN * HIDDEN + 255) / 256, 256, 0, stream>>>(W3, Bt3, HIDDEN);

    int gemm_blocks = (HIDDEN / 128) * (M_PAD / 256);   // 784 = 98*8, 1D for XCD swizzle

    // layer 1: GA = agg(x);  F = tanh(GA @ W1' + b1)
    agg1_kernel<<<(N_NODES + 7) / 8, 256, 0, stream>>>(x, dis, off, csr_src, GA);
    gemm_mfma_kernel<<<gemm_blocks, 512, 0, stream>>>(GA, Bt1, b1, F, N_NODES, IN_DIM);
    // layer 2
    agg_f16_kernel<<<(N_NODES + 3) / 4, 256, 0, stream>>>(F, dis, off, csr_src, GA);
    gemm_mfma_kernel<<<gemm_blocks, 512, 0, stream>>>(GA, Bt2, b2, F, N_NODES, HIDDEN);
    // layer 3
    agg_f16_kernel<<<(N_NODES + 3) / 4, 256, 0, stream>>>(F, dis, off, csr_src, GA);
    gemm_mfma_kernel<<<gemm_blocks, 512, 0, stream>>>(GA, Bt3, b3, F, N_NODES, HIDDEN);
    // final scoring
    edge_score_kernel<<<(N_TRAIN + 3) / 4, 256, 0, stream>>>(F, srcp, dstp, te, fc2W, fc2b,
                                                             (float*)d_out);
}

// Round 10
// 489.894 us; speedup vs baseline: 1.2472x; 1.2472x over previous
//
#include <hip/hip_runtime.h>
#include <math.h>

#define N_NODES 50000
#define N_EDGES 400000
#define N_TRAIN 50000
#define IN_DIM  128
#define HIDDEN  512
#define M_PAD   50048   // 391 * 128

typedef _Float16 f16;
typedef __attribute__((ext_vector_type(8))) _Float16 f16x8;
typedef __attribute__((ext_vector_type(4))) _Float16 f16x4;
typedef __attribute__((ext_vector_type(4))) float f32x4;

// ---------------- graph preprocessing ----------------

__global__ void count_dst_kernel(const int* __restrict__ dst, int* __restrict__ cnt) {
    int i = blockIdx.x * blockDim.x + threadIdx.x;
    if (i < N_EDGES) atomicAdd(&cnt[dst[i]], 1);
}

__global__ void dis_kernel(const int* __restrict__ cnt, float* __restrict__ dis) {
    int v = blockIdx.x * blockDim.x + threadIdx.x;
    if (v < N_NODES) dis[v] = rsqrtf(1.0f + (float)cnt[v]);  // +1 self-loop
}

__global__ void scan_kernel(const int* __restrict__ cnt, int* __restrict__ off) {
    __shared__ int part[1024];
    const int T = 1024;
    const int chunk = (N_NODES + T - 1) / T;
    int t = threadIdx.x;
    int s = t * chunk, e = min(s + chunk, N_NODES);
    int sum = 0;
    for (int i = s; i < e; i++) sum += cnt[i];
    part[t] = sum;
    __syncthreads();
    for (int o = 1; o < T; o <<= 1) {
        int v = (t >= o) ? part[t - o] : 0;
        __syncthreads();
        part[t] += v;
        __syncthreads();
    }
    int run = part[t] - sum;
    for (int i = s; i < e; i++) { off[i] = run; run += cnt[i]; }
    if (t == T - 1) off[N_NODES] = run;
}

// CSR fill; also precompute per-edge src-side norm weight (kills the random
// dis[s] gather in the agg inner loop).
__global__ void fill_csr_kernel(const int* __restrict__ src, const int* __restrict__ dst,
                                const int* __restrict__ off, int* __restrict__ cursor,
                                const float* __restrict__ dis,
                                int* __restrict__ csr_src, float* __restrict__ csr_w) {
    int i = blockIdx.x * blockDim.x + threadIdx.x;
    if (i < N_EDGES) {
        int d = dst[i], s = src[i];
        int p = atomicAdd(&cursor[d], 1);
        int idx = off[d] + p;
        csr_src[idx] = s;
        csr_w[idx] = dis[s];
    }
}

// ------------- weight conversion: W[K][512] -> Bt[512][2K] = [hi | lo] rows -------------
__global__ void convw_kernel(const float* __restrict__ W, f16* __restrict__ Bt, int K) {
    int idx = blockIdx.x * blockDim.x + threadIdx.x;
    if (idx >= K * HIDDEN) return;
    int k = idx / HIDDEN, n = idx % HIDDEN;
    float w = W[(size_t)k * HIDDEN + n];
    f16 hi = (f16)w;
    f16 lo = (f16)(w - (float)hi);
    size_t base = (size_t)n * 2 * K;
    Bt[base + k]     = hi;
    Bt[base + K + k] = lo;
}

// ------------- layer-1 aggregation: f32 x (D=128) -> fp16 (stride 128) -------------
__global__ void agg1_kernel(const float* __restrict__ x, const float* __restrict__ dis,
                            const int* __restrict__ off, const int* __restrict__ csr_src,
                            const float* __restrict__ csr_w, f16* __restrict__ A) {
    const int TPN = 32;   // 128/4
    int node = blockIdx.x * 8 + threadIdx.x / TPN;
    if (node >= N_NODES) return;
    int t = threadIdx.x % TPN;
    float dv = dis[node];
    float w0 = dv * dv;
    float4 a = ((const float4*)(x + (size_t)node * IN_DIM))[t];
    float4 acc = make_float4(a.x * w0, a.y * w0, a.z * w0, a.w * w0);
    int s0 = off[node], s1 = off[node + 1];
    for (int k = s0; k < s1; k++) {
        int s = csr_src[k];
        float w = csr_w[k] * dv;
        float4 b = ((const float4*)(x + (size_t)s * IN_DIM))[t];
        acc.x = fmaf(w, b.x, acc.x);
        acc.y = fmaf(w, b.y, acc.y);
        acc.z = fmaf(w, b.z, acc.z);
        acc.w = fmaf(w, b.w, acc.w);
    }
    f16x4 o;
    o.x = (f16)acc.x; o.y = (f16)acc.y; o.z = (f16)acc.z; o.w = (f16)acc.w;
    *(f16x4*)&A[(size_t)node * IN_DIM + t * 4] = o;
}

// ------------- aggregation: fp16 h (512) -> fp16 (stride 512), 2-way unrolled -------------
__global__ void agg_f16_kernel(const f16* __restrict__ h, const float* __restrict__ dis,
                               const int* __restrict__ off, const int* __restrict__ csr_src,
                               const float* __restrict__ csr_w, f16* __restrict__ A) {
    const int TPN = 64;   // 512/8, one wave per node
    int node = blockIdx.x * 4 + threadIdx.x / TPN;
    if (node >= N_NODES) return;
    int t = threadIdx.x % TPN;
    float dv = dis[node];
    float w0 = dv * dv;
    f16x8 a = *(const f16x8*)&h[(size_t)node * HIDDEN + t * 8];
    float acc0[8], acc1[8];
    #pragma unroll
    for (int j = 0; j < 8; j++) { acc0[j] = w0 * (float)a[j]; acc1[j] = 0.f; }
    int s0 = off[node], s1 = off[node + 1];
    int k = s0;
    for (; k + 2 <= s1; k += 2) {      // two independent gathers in flight
        int sa = csr_src[k], sb = csr_src[k + 1];
        float wa = csr_w[k] * dv, wb = csr_w[k + 1] * dv;
        f16x8 ba = *(const f16x8*)&h[(size_t)sa * HIDDEN + t * 8];
        f16x8 bb = *(const f16x8*)&h[(size_t)sb * HIDDEN + t * 8];
        #pragma unroll
        for (int j = 0; j < 8; j++) acc0[j] = fmaf(wa, (float)ba[j], acc0[j]);
        #pragma unroll
        for (int j = 0; j < 8; j++) acc1[j] = fmaf(wb, (float)bb[j], acc1[j]);
    }
    if (k < s1) {
        int sa = csr_src[k];
        float wa = csr_w[k] * dv;
        f16x8 ba = *(const f16x8*)&h[(size_t)sa * HIDDEN + t * 8];
        #pragma unroll
        for (int j = 0; j < 8; j++) acc0[j] = fmaf(wa, (float)ba[j], acc0[j]);
    }
    f16x8 o;
    #pragma unroll
    for (int j = 0; j < 8; j++) o[j] = (f16)(acc0[j] + acc1[j]);
    *(f16x8*)&A[(size_t)node * HIDDEN + t * 8] = o;
}

// ------- MFMA fp16 GEMM, m97-style: 128x128 tile, 4 waves, single-buffer, 3 blocks/CU ------
// C[M][512] = tanh(A @ (B_hi + B_lo) + bias).  BK=64 physical K per step; A staged once,
// used against both B_hi and B_lo (64 MFMA/wave/barrier-pair).  48 KB LDS -> 3 blocks/CU.
// ROUND-9 BUG FIX: B staging loop was i<2 (512 slots) but each B half-tile is 1024 slots
// (128 rows x 64 f16) -> rows 64..127 of Bs were never staged -> NaN. Now i<4.
// XOR-swizzle per rule #21 (linear LDS dest + inverse-swizzled global src + swizzled read).
// Epilogue: acc -> LDS (stride 136 f16 = 17x16B, keeps f16x8 slots 16B-aligned) ->
// coalesced f16x8 stores.
__global__ __launch_bounds__(256, 3) void gemm_mfma_kernel(
    const f16* __restrict__ A, const f16* __restrict__ Bt, const float* __restrict__ bias,
    f16* __restrict__ C, int M, int Kb) {
    __shared__ f16 smem[24576];          // 48 KB: As[8192] | Bhi[8192] | Blo[8192]
    f16* As  = smem;
    f16* Bs0 = smem + 8192;              // Bs0 + v*8192
    const int Kp = 2 * Kb;
    int tid = threadIdx.x;
    int lane = tid & 63, wv = tid >> 6;
    int wr = wv >> 1, wc = wv & 1;       // 2x2 waves, 64x64 output each

    // bijective XCD swizzle (m204); grid 1564 = 4 * 391
    int nwg = gridDim.x;
    int q = nwg >> 3, r = nwg & 7;
    int xcd = blockIdx.x & 7, pos = blockIdx.x >> 3;
    int wgid = (xcd < r ? xcd * (q + 1) : r * (q + 1) + (xcd - r) * q) + pos;
    int j0 = (wgid & 3) * 128;           // 4 col tiles
    int i0 = (wgid >> 2) * 128;          // 391 row tiles

    int l15 = lane & 15, l4 = lane >> 4;

    f32x4 acc[4][4];
    #pragma unroll
    for (int m = 0; m < 4; m++)
        #pragma unroll
        for (int n = 0; n < 4; n++)
            acc[m][n] = (f32x4){0.f, 0.f, 0.f, 0.f};

    const int nt = Kb / 64;
    for (int t = 0; t < nt; t++) {
        int k0 = t * 64;
        if (t) __syncthreads();          // previous step's readers done -> LDS reusable
        #pragma unroll
        for (int i = 0; i < 4; i++) {    // A: 128x64 = 1024 slots (4 loads/thread)
            int s = i * 256 + tid;
            int row = s >> 3, c8 = s & 7;
            int c8s = c8 ^ (row & 7);    // inverse-swizzled source column
            const f16* gp = A + (size_t)(i0 + row) * Kb + k0 + c8s * 8;
            f16* lp = &As[(i * 256 + wv * 64) * 8];   // wave-uniform base
            __builtin_amdgcn_global_load_lds(
                (const __attribute__((address_space(1))) void*)gp,
                (__attribute__((address_space(3))) void*)lp, 16, 0, 0);
        }
        #pragma unroll
        for (int v = 0; v < 2; v++)      // B hi/lo: 1024 slots EACH (4 loads/thread each)
            #pragma unroll
            for (int i = 0; i < 4; i++) {
                int s = i * 256 + tid;
                int row = s >> 3, c8 = s & 7;
                int c8s = c8 ^ (row & 7);
                const f16* gp = Bt + (size_t)(j0 + row) * Kp + v * Kb + k0 + c8s * 8;
                f16* lp = &Bs0[(v * 1024 + i * 256 + wv * 64) * 8];
                __builtin_amdgcn_global_load_lds(
                    (const __attribute__((address_space(1))) void*)gp,
                    (__attribute__((address_space(3))) void*)lp, 16, 0, 0);
            }
        __syncthreads();                 // drain vmcnt -> tiles resident

        f16x8 af[4][2], bfr[4][2][2];
        #pragma unroll
        for (int m = 0; m < 4; m++) {
            int row = wr * 64 + m * 16 + l15;
            #pragma unroll
            for (int kk = 0; kk < 2; kk++) {
                int slot = (kk * 4 + l4) ^ (row & 7);
                af[m][kk] = *(const f16x8*)&As[row * 64 + slot * 8];
            }
        }
        #pragma unroll
        for (int n = 0; n < 4; n++) {
            int brow = wc * 64 + n * 16 + l15;
            #pragma unroll
            for (int v = 0; v < 2; v++)
                #pragma unroll
                for (int kk = 0; kk < 2; kk++) {
                    int slot = (kk * 4 + l4) ^ (brow & 7);
                    bfr[n][v][kk] = *(const f16x8*)&Bs0[v * 8192 + brow * 64 + slot * 8];
                }
        }
        #pragma unroll
        for (int m = 0; m < 4; m++)
            #pragma unroll
            for (int n = 0; n < 4; n++)
                #pragma unroll
                for (int v = 0; v < 2; v++)
                    #pragma unroll
                    for (int kk = 0; kk < 2; kk++)
                        acc[m][n] = __builtin_amdgcn_mfma_f32_16x16x32_f16(
                            af[m][kk], bfr[n][v][kk], acc[m][n], 0, 0, 0);
    }

    // ---- epilogue: acc -> LDS (stride 136 = 16B-aligned slots) -> coalesced stores ----
    __syncthreads();                     // all waves done reading K-loop LDS
    #pragma unroll
    for (int m = 0; m < 4; m++) {
        #pragma unroll
        for (int n = 0; n < 4; n++) {
            int lcol = wc * 64 + n * 16 + l15;
            float bc = bias[j0 + lcol];
            #pragma unroll
            for (int rr = 0; rr < 4; rr++) {
                int lrow = wr * 64 + m * 16 + l4 * 4 + rr;
                smem[lrow * 136 + lcol] = (f16)tanhf(acc[m][n][rr] + bc);
            }
        }
    }
    __syncthreads();
    #pragma unroll
    for (int j = 0; j < 8; j++) {        // 128 rows x 16 chunks of 16B
        int qq = j * 256 + tid;
        int row = qq >> 4, c8 = qq & 15;
        int grow = i0 + row;
        if (grow < M)
            *(f16x8*)&C[(size_t)grow * HIDDEN + j0 + c8 * 8] =
                *(const f16x8*)&smem[row * 136 + c8 * 8];
    }
}

// ---------------- final edge scoring (fp16 input) ----------------
__global__ void edge_score_kernel(const f16* __restrict__ h,
                                  const int* __restrict__ src, const int* __restrict__ dst,
                                  const int* __restrict__ te, const float* __restrict__ wgt,
                                  const float* __restrict__ fc2b, float* __restrict__ out) {
    int wid = threadIdx.x / 64;
    int lane = threadIdx.x % 64;
    int e = blockIdx.x * 4 + wid;
    if (e >= N_TRAIN) return;
    int id = te[e];
    int a = src[id], b = dst[id];
    f16x8 ha = *(const f16x8*)&h[(size_t)a * HIDDEN + lane * 8];
    f16x8 hb = *(const f16x8*)&h[(size_t)b * HIDDEN + lane * 8];
    float4 w0 = *(const float4*)&wgt[lane * 8];
    float4 w1 = *(const float4*)&wgt[lane * 8 + 4];
    float acc = 0.f;
    acc += (float)ha[0] * (float)hb[0] * w0.x;
    acc += (float)ha[1] * (float)hb[1] * w0.y;
    acc += (float)ha[2] * (float)hb[2] * w0.z;
    acc += (float)ha[3] * (float)hb[3] * w0.w;
    acc += (float)ha[4] * (float)hb[4] * w1.x;
    acc += (float)ha[5] * (float)hb[5] * w1.y;
    acc += (float)ha[6] * (float)hb[6] * w1.z;
    acc += (float)ha[7] * (float)hb[7] * w1.w;
    #pragma unroll
    for (int o = 32; o > 0; o >>= 1) acc += __shfl_down(acc, o);
    if (lane == 0) out[e] = acc + fc2b[0];
}

// ---------------- launch ----------------

extern "C" void kernel_launch(void* const* d_in, const int* in_sizes, int n_in,
                              void* d_out, int out_size, void* d_ws, size_t ws_size,
                              hipStream_t stream) {
    const float* x    = (const float*)d_in[0];
    const int*   eidx = (const int*)d_in[1];
    const int*   te   = (const int*)d_in[2];
    const float* W1   = (const float*)d_in[3];
    const float* b1   = (const float*)d_in[4];
    const float* W2   = (const float*)d_in[5];
    const float* b2   = (const float*)d_in[6];
    const float* W3   = (const float*)d_in[7];
    const float* b3   = (const float*)d_in[8];
    const float* fc2W = (const float*)d_in[9];
    const float* fc2b = (const float*)d_in[10];
    const int* srcp = eidx;
    const int* dstp = eidx + N_EDGES;

    char* ws = (char*)d_ws;
    size_t used = 0;
    auto alloc = [&](size_t bytes) {
        void* p = ws + used;
        used += (bytes + 255) / 256 * 256;
        return p;
    };
    int*   cnt     = (int*)alloc((size_t)N_NODES * 4);
    int*   off     = (int*)alloc((size_t)(N_NODES + 1) * 4);
    int*   cursor  = (int*)alloc((size_t)N_NODES * 4);
    int*   csr_src = (int*)alloc((size_t)N_EDGES * 4);
    float* csr_w   = (float*)alloc((size_t)N_EDGES * 4);
    float* dis     = (float*)alloc((size_t)N_NODES * 4);
    f16* Bt1 = (f16*)alloc((size_t)HIDDEN * 2 * IN_DIM * 2);
    f16* Bt2 = (f16*)alloc((size_t)HIDDEN * 2 * HIDDEN * 2);
    f16* Bt3 = (f16*)alloc((size_t)HIDDEN * 2 * HIDDEN * 2);
    f16* GA  = (f16*)alloc((size_t)M_PAD * HIDDEN * 2);   // GEMM A operand
    f16* F   = (f16*)alloc((size_t)M_PAD * HIDDEN * 2);   // layer output

    if (used > ws_size) return;  // fail cleanly rather than OOB

    hipMemsetAsync(cnt, 0, (size_t)N_NODES * 4, stream);
    hipMemsetAsync(cursor, 0, (size_t)N_NODES * 4, stream);

    count_dst_kernel<<<(N_EDGES + 255) / 256, 256, 0, stream>>>(dstp, cnt);
    dis_kernel<<<(N_NODES + 255) / 256, 256, 0, stream>>>(cnt, dis);
    scan_kernel<<<1, 1024, 0, stream>>>(cnt, off);
    fill_csr_kernel<<<(N_EDGES + 255) / 256, 256, 0, stream>>>(srcp, dstp, off, cursor, dis,
                                                               csr_src, csr_w);

    convw_kernel<<<(IN_DIM * HIDDEN + 255) / 256, 256, 0, stream>>>(W1, Bt1, IN_DIM);
    convw_kernel<<<(HIDDEN * HIDDEN + 255) / 256, 256, 0, stream>>>(W2, Bt2, HIDDEN);
    convw_kernel<<<(HIDDEN * HIDDEN + 255) / 256, 256, 0, stream>>>(W3, Bt3, HIDDEN);

    int gemm_blocks = (HIDDEN / 128) * (M_PAD / 128);   // 1564, 1D for XCD swizzle

    // layer 1: GA = agg(x);  F = tanh(GA @ W1' + b1)
    agg1_kernel<<<(N_NODES + 7) / 8, 256, 0, stream>>>(x, dis, off, csr_src, csr_w, GA);
    gemm_mfma_kernel<<<gemm_blocks, 256, 0, stream>>>(GA, Bt1, b1, F, N_NODES, IN_DIM);
    // layer 2
    agg_f16_kernel<<<(N_NODES + 3) / 4, 256, 0, stream>>>(F, dis, off, csr_src, csr_w, GA);
    gemm_mfma_kernel<<<gemm_blocks, 256, 0, stream>>>(GA, Bt2, b2, F, N_NODES, HIDDEN);
    // layer 3
    agg_f16_kernel<<<(N_NODES + 3) / 4, 256, 0, stream>>>(F, dis, off, csr_src, csr_w, GA);
    gemm_mfma_kernel<<<gemm_blocks, 256, 0, stream>>>(GA, Bt3, b3, F, N_NODES, HIDDEN);
    // final scoring
    edge_score_kernel<<<(N_TRAIN + 3) / 4, 256, 0, stream>>>(F, srcp, dstp, te, fc2W, fc2b,
                                                             (float*)d_out);
}

// Round 11
// 417.675 us; speedup vs baseline: 1.4628x; 1.1729x over previous
//
#include <hip/hip_runtime.h>
#include <math.h>

#define N_NODES 50000
#define N_EDGES 400000
#define N_TRAIN 50000
#define IN_DIM  128
#define HIDDEN  512
#define M_PAD   50048   // 391 * 128
#define SCAN_B  196     // 196 * 256 = 50176 >= N_NODES

typedef _Float16 f16;
typedef __attribute__((ext_vector_type(8))) _Float16 f16x8;
typedef __attribute__((ext_vector_type(4))) _Float16 f16x4;
typedef __attribute__((ext_vector_type(4))) float f32x4;

// ---------------- graph preprocessing ----------------

__global__ void count_dst_kernel(const int* __restrict__ dst, int* __restrict__ cnt) {
    int i = blockIdx.x * blockDim.x + threadIdx.x;
    if (i < N_EDGES) atomicAdd(&cnt[dst[i]], 1);
}

__global__ void dis_kernel(const int* __restrict__ cnt, float* __restrict__ dis) {
    int v = blockIdx.x * blockDim.x + threadIdx.x;
    if (v < N_NODES) dis[v] = rsqrtf(1.0f + (float)cnt[v]);  // +1 self-loop
}

// ---- hierarchical scan (replaces 76us single-block scan: 0.14% occupancy bottleneck) ----
// S1: per-block sums.  S2: scan the 196 partials (1 tiny block).  S3: local scan + base.
__global__ void scan1_kernel(const int* __restrict__ cnt, int* __restrict__ bsum) {
    __shared__ int red[256];
    int t = threadIdx.x, i = blockIdx.x * 256 + t;
    red[t] = (i < N_NODES) ? cnt[i] : 0;
    __syncthreads();
    for (int o = 128; o > 0; o >>= 1) {
        if (t < o) red[t] += red[t + o];
        __syncthreads();
    }
    if (t == 0) bsum[blockIdx.x] = red[0];
}

__global__ void scan2_kernel(const int* __restrict__ bsum, int* __restrict__ boff) {
    __shared__ int part[256];
    int t = threadIdx.x;
    int v = (t < SCAN_B) ? bsum[t] : 0;
    part[t] = v;
    __syncthreads();
    for (int o = 1; o < 256; o <<= 1) {
        int u = (t >= o) ? part[t - o] : 0;
        __syncthreads();
        part[t] += u;
        __syncthreads();
    }
    if (t < SCAN_B) boff[t] = part[t] - v;   // exclusive
}

__global__ void scan3_kernel(const int* __restrict__ cnt, const int* __restrict__ boff,
                             int* __restrict__ off) {
    __shared__ int part[256];
    int t = threadIdx.x, i = blockIdx.x * 256 + t;
    int v = (i < N_NODES) ? cnt[i] : 0;
    part[t] = v;
    __syncthreads();
    for (int o = 1; o < 256; o <<= 1) {
        int u = (t >= o) ? part[t - o] : 0;
        __syncthreads();
        part[t] += u;
        __syncthreads();
    }
    int excl = part[t] - v;
    int base = boff[blockIdx.x];
    if (i < N_NODES) off[i] = base + excl;
    if (i == N_NODES - 1) off[N_NODES] = base + excl + v;   // total
}

// CSR fill; also precompute per-edge src-side norm weight.
__global__ void fill_csr_kernel(const int* __restrict__ src, const int* __restrict__ dst,
                                const int* __restrict__ off, int* __restrict__ cursor,
                                const float* __restrict__ dis,
                                int* __restrict__ csr_src, float* __restrict__ csr_w) {
    int i = blockIdx.x * blockDim.x + threadIdx.x;
    if (i < N_EDGES) {
        int d = dst[i], s = src[i];
        int p = atomicAdd(&cursor[d], 1);
        int idx = off[d] + p;
        csr_src[idx] = s;
        csr_w[idx] = dis[s];
    }
}

// ------------- weight conversion: W[K][512] -> Bt[512][2K] = [hi | lo] rows -------------
__global__ void convw_kernel(const float* __restrict__ W, f16* __restrict__ Bt, int K) {
    int idx = blockIdx.x * blockDim.x + threadIdx.x;
    if (idx >= K * HIDDEN) return;
    int k = idx / HIDDEN, n = idx % HIDDEN;
    float w = W[(size_t)k * HIDDEN + n];
    f16 hi = (f16)w;
    f16 lo = (f16)(w - (float)hi);
    size_t base = (size_t)n * 2 * K;
    Bt[base + k]     = hi;
    Bt[base + K + k] = lo;
}

// ------------- layer-1 aggregation: f32 x (D=128) -> fp16, 2-way unrolled -------------
__global__ void agg1_kernel(const float* __restrict__ x, const float* __restrict__ dis,
                            const int* __restrict__ off, const int* __restrict__ csr_src,
                            const float* __restrict__ csr_w, f16* __restrict__ A) {
    const int TPN = 32;   // 128/4
    int node = blockIdx.x * 8 + threadIdx.x / TPN;
    if (node >= N_NODES) return;
    int t = threadIdx.x % TPN;
    float dv = dis[node];
    float w0 = dv * dv;
    float4 a = ((const float4*)(x + (size_t)node * IN_DIM))[t];
    float4 acc = make_float4(a.x * w0, a.y * w0, a.z * w0, a.w * w0);
    float4 acc1 = make_float4(0.f, 0.f, 0.f, 0.f);
    int s0 = off[node], s1 = off[node + 1];
    int k = s0;
    for (; k + 2 <= s1; k += 2) {
        int sa = csr_src[k], sb = csr_src[k + 1];
        float wa = csr_w[k] * dv, wb = csr_w[k + 1] * dv;
        float4 ba = ((const float4*)(x + (size_t)sa * IN_DIM))[t];
        float4 bb = ((const float4*)(x + (size_t)sb * IN_DIM))[t];
        acc.x = fmaf(wa, ba.x, acc.x);   acc.y = fmaf(wa, ba.y, acc.y);
        acc.z = fmaf(wa, ba.z, acc.z);   acc.w = fmaf(wa, ba.w, acc.w);
        acc1.x = fmaf(wb, bb.x, acc1.x); acc1.y = fmaf(wb, bb.y, acc1.y);
        acc1.z = fmaf(wb, bb.z, acc1.z); acc1.w = fmaf(wb, bb.w, acc1.w);
    }
    if (k < s1) {
        int sa = csr_src[k];
        float wa = csr_w[k] * dv;
        float4 ba = ((const float4*)(x + (size_t)sa * IN_DIM))[t];
        acc.x = fmaf(wa, ba.x, acc.x); acc.y = fmaf(wa, ba.y, acc.y);
        acc.z = fmaf(wa, ba.z, acc.z); acc.w = fmaf(wa, ba.w, acc.w);
    }
    f16x4 o;
    o.x = (f16)(acc.x + acc1.x); o.y = (f16)(acc.y + acc1.y);
    o.z = (f16)(acc.z + acc1.z); o.w = (f16)(acc.w + acc1.w);
    *(f16x4*)&A[(size_t)node * IN_DIM + t * 4] = o;
}

// ------- aggregation: fp16 h (512) -> fp16, 4-way unrolled (4 gathers in flight) -------
__global__ void agg_f16_kernel(const f16* __restrict__ h, const float* __restrict__ dis,
                               const int* __restrict__ off, const int* __restrict__ csr_src,
                               const float* __restrict__ csr_w, f16* __restrict__ A) {
    const int TPN = 64;   // 512/8, one wave per node
    int node = blockIdx.x * 4 + threadIdx.x / TPN;
    if (node >= N_NODES) return;
    int t = threadIdx.x % TPN;
    float dv = dis[node];
    float w0 = dv * dv;
    f16x8 a = *(const f16x8*)&h[(size_t)node * HIDDEN + t * 8];
    float acc0[8], acc1[8];
    #pragma unroll
    for (int j = 0; j < 8; j++) { acc0[j] = w0 * (float)a[j]; acc1[j] = 0.f; }
    int s0 = off[node], s1 = off[node + 1];
    int k = s0;
    for (; k + 4 <= s1; k += 4) {      // four independent row gathers in flight
        int sa = csr_src[k],     sb = csr_src[k + 1];
        int sc = csr_src[k + 2], sd = csr_src[k + 3];
        float wa = csr_w[k] * dv,     wb = csr_w[k + 1] * dv;
        float wc = csr_w[k + 2] * dv, wd = csr_w[k + 3] * dv;
        f16x8 ba = *(const f16x8*)&h[(size_t)sa * HIDDEN + t * 8];
        f16x8 bb = *(const f16x8*)&h[(size_t)sb * HIDDEN + t * 8];
        f16x8 bc = *(const f16x8*)&h[(size_t)sc * HIDDEN + t * 8];
        f16x8 bd = *(const f16x8*)&h[(size_t)sd * HIDDEN + t * 8];
        #pragma unroll
        for (int j = 0; j < 8; j++) {
            acc0[j] = fmaf(wa, (float)ba[j], acc0[j]);
            acc1[j] = fmaf(wb, (float)bb[j], acc1[j]);
            acc0[j] = fmaf(wc, (float)bc[j], acc0[j]);
            acc1[j] = fmaf(wd, (float)bd[j], acc1[j]);
        }
    }
    for (; k < s1; k++) {
        int sa = csr_src[k];
        float wa = csr_w[k] * dv;
        f16x8 ba = *(const f16x8*)&h[(size_t)sa * HIDDEN + t * 8];
        #pragma unroll
        for (int j = 0; j < 8; j++) acc0[j] = fmaf(wa, (float)ba[j], acc0[j]);
    }
    f16x8 o;
    #pragma unroll
    for (int j = 0; j < 8; j++) o[j] = (f16)(acc0[j] + acc1[j]);
    *(f16x8*)&A[(size_t)node * HIDDEN + t * 8] = o;
}

// ------- MFMA fp16 GEMM, m97-style: 128x128 tile, 4 waves, single-buffer, 3 blocks/CU ------
// (unchanged from round 10 — verified passing)
__global__ __launch_bounds__(256, 3) void gemm_mfma_kernel(
    const f16* __restrict__ A, const f16* __restrict__ Bt, const float* __restrict__ bias,
    f16* __restrict__ C, int M, int Kb) {
    __shared__ f16 smem[24576];          // 48 KB: As[8192] | Bhi[8192] | Blo[8192]
    f16* As  = smem;
    f16* Bs0 = smem + 8192;              // Bs0 + v*8192
    const int Kp = 2 * Kb;
    int tid = threadIdx.x;
    int lane = tid & 63, wv = tid >> 6;
    int wr = wv >> 1, wc = wv & 1;       // 2x2 waves, 64x64 output each

    // bijective XCD swizzle (m204); grid 1564 = 4 * 391
    int nwg = gridDim.x;
    int q = nwg >> 3, r = nwg & 7;
    int xcd = blockIdx.x & 7, pos = blockIdx.x >> 3;
    int wgid = (xcd < r ? xcd * (q + 1) : r * (q + 1) + (xcd - r) * q) + pos;
    int j0 = (wgid & 3) * 128;           // 4 col tiles
    int i0 = (wgid >> 2) * 128;          // 391 row tiles

    int l15 = lane & 15, l4 = lane >> 4;

    f32x4 acc[4][4];
    #pragma unroll
    for (int m = 0; m < 4; m++)
        #pragma unroll
        for (int n = 0; n < 4; n++)
            acc[m][n] = (f32x4){0.f, 0.f, 0.f, 0.f};

    const int nt = Kb / 64;
    for (int t = 0; t < nt; t++) {
        int k0 = t * 64;
        if (t) __syncthreads();          // previous step's readers done -> LDS reusable
        #pragma unroll
        for (int i = 0; i < 4; i++) {    // A: 128x64 = 1024 slots (4 loads/thread)
            int s = i * 256 + tid;
            int row = s >> 3, c8 = s & 7;
            int c8s = c8 ^ (row & 7);    // inverse-swizzled source column
            const f16* gp = A + (size_t)(i0 + row) * Kb + k0 + c8s * 8;
            f16* lp = &As[(i * 256 + wv * 64) * 8];   // wave-uniform base
            __builtin_amdgcn_global_load_lds(
                (const __attribute__((address_space(1))) void*)gp,
                (__attribute__((address_space(3))) void*)lp, 16, 0, 0);
        }
        #pragma unroll
        for (int v = 0; v < 2; v++)      // B hi/lo: 1024 slots EACH (4 loads/thread each)
            #pragma unroll
            for (int i = 0; i < 4; i++) {
                int s = i * 256 + tid;
                int row = s >> 3, c8 = s & 7;
                int c8s = c8 ^ (row & 7);
                const f16* gp = Bt + (size_t)(j0 + row) * Kp + v * Kb + k0 + c8s * 8;
                f16* lp = &Bs0[(v * 1024 + i * 256 + wv * 64) * 8];
                __builtin_amdgcn_global_load_lds(
                    (const __attribute__((address_space(1))) void*)gp,
                    (__attribute__((address_space(3))) void*)lp, 16, 0, 0);
            }
        __syncthreads();                 // drain vmcnt -> tiles resident

        f16x8 af[4][2], bfr[4][2][2];
        #pragma unroll
        for (int m = 0; m < 4; m++) {
            int row = wr * 64 + m * 16 + l15;
            #pragma unroll
            for (int kk = 0; kk < 2; kk++) {
                int slot = (kk * 4 + l4) ^ (row & 7);
                af[m][kk] = *(const f16x8*)&As[row * 64 + slot * 8];
            }
        }
        #pragma unroll
        for (int n = 0; n < 4; n++) {
            int brow = wc * 64 + n * 16 + l15;
            #pragma unroll
            for (int v = 0; v < 2; v++)
                #pragma unroll
                for (int kk = 0; kk < 2; kk++) {
                    int slot = (kk * 4 + l4) ^ (brow & 7);
                    bfr[n][v][kk] = *(const f16x8*)&Bs0[v * 8192 + brow * 64 + slot * 8];
                }
        }
        #pragma unroll
        for (int m = 0; m < 4; m++)
            #pragma unroll
            for (int n = 0; n < 4; n++)
                #pragma unroll
                for (int v = 0; v < 2; v++)
                    #pragma unroll
                    for (int kk = 0; kk < 2; kk++)
                        acc[m][n] = __builtin_amdgcn_mfma_f32_16x16x32_f16(
                            af[m][kk], bfr[n][v][kk], acc[m][n], 0, 0, 0);
    }

    // ---- epilogue: acc -> LDS (stride 136 = 16B-aligned slots) -> coalesced stores ----
    __syncthreads();                     // all waves done reading K-loop LDS
    #pragma unroll
    for (int m = 0; m < 4; m++) {
        #pragma unroll
        for (int n = 0; n < 4; n++) {
            int lcol = wc * 64 + n * 16 + l15;
            float bc = bias[j0 + lcol];
            #pragma unroll
            for (int rr = 0; rr < 4; rr++) {
                int lrow = wr * 64 + m * 16 + l4 * 4 + rr;
                smem[lrow * 136 + lcol] = (f16)tanhf(acc[m][n][rr] + bc);
            }
        }
    }
    __syncthreads();
    #pragma unroll
    for (int j = 0; j < 8; j++) {        // 128 rows x 16 chunks of 16B
        int qq = j * 256 + tid;
        int row = qq >> 4, c8 = qq & 15;
        int grow = i0 + row;
        if (grow < M)
            *(f16x8*)&C[(size_t)grow * HIDDEN + j0 + c8 * 8] =
                *(const f16x8*)&smem[row * 136 + c8 * 8];
    }
}

// ---------------- final edge scoring (fp16 input) ----------------
__global__ void edge_score_kernel(const f16* __restrict__ h,
                                  const int* __restrict__ src, const int* __restrict__ dst,
                                  const int* __restrict__ te, const float* __restrict__ wgt,
                                  const float* __restrict__ fc2b, float* __restrict__ out) {
    int wid = threadIdx.x / 64;
    int lane = threadIdx.x % 64;
    int e = blockIdx.x * 4 + wid;
    if (e >= N_TRAIN) return;
    int id = te[e];
    int a = src[id], b = dst[id];
    f16x8 ha = *(const f16x8*)&h[(size_t)a * HIDDEN + lane * 8];
    f16x8 hb = *(const f16x8*)&h[(size_t)b * HIDDEN + lane * 8];
    float4 w0 = *(const float4*)&wgt[lane * 8];
    float4 w1 = *(const float4*)&wgt[lane * 8 + 4];
    float acc = 0.f;
    acc += (float)ha[0] * (float)hb[0] * w0.x;
    acc += (float)ha[1] * (float)hb[1] * w0.y;
    acc += (float)ha[2] * (float)hb[2] * w0.z;
    acc += (float)ha[3] * (float)hb[3] * w0.w;
    acc += (float)ha[4] * (float)hb[4] * w1.x;
    acc += (float)ha[5] * (float)hb[5] * w1.y;
    acc += (float)ha[6] * (float)hb[6] * w1.z;
    acc += (float)ha[7] * (float)hb[7] * w1.w;
    #pragma unroll
    for (int o = 32; o > 0; o >>= 1) acc += __shfl_down(acc, o);
    if (lane == 0) out[e] = acc + fc2b[0];
}

// ---------------- launch ----------------

extern "C" void kernel_launch(void* const* d_in, const int* in_sizes, int n_in,
                              void* d_out, int out_size, void* d_ws, size_t ws_size,
                              hipStream_t stream) {
    const float* x    = (const float*)d_in[0];
    const int*   eidx = (const int*)d_in[1];
    const int*   te   = (const int*)d_in[2];
    const float* W1   = (const float*)d_in[3];
    const float* b1   = (const float*)d_in[4];
    const float* W2   = (const float*)d_in[5];
    const float* b2   = (const float*)d_in[6];
    const float* W3   = (const float*)d_in[7];
    const float* b3   = (const float*)d_in[8];
    const float* fc2W = (const float*)d_in[9];
    const float* fc2b = (const float*)d_in[10];
    const int* srcp = eidx;
    const int* dstp = eidx + N_EDGES;

    char* ws = (char*)d_ws;
    size_t used = 0;
    auto alloc = [&](size_t bytes) {
        void* p = ws + used;
        used += (bytes + 255) / 256 * 256;
        return p;
    };
    int*   cnt     = (int*)alloc((size_t)N_NODES * 4);
    int*   off     = (int*)alloc((size_t)(N_NODES + 1) * 4);
    int*   cursor  = (int*)alloc((size_t)N_NODES * 4);
    int*   bsum    = (int*)alloc((size_t)SCAN_B * 4);
    int*   boff    = (int*)alloc((size_t)SCAN_B * 4);
    int*   csr_src = (int*)alloc((size_t)N_EDGES * 4);
    float* csr_w   = (float*)alloc((size_t)N_EDGES * 4);
    float* dis     = (float*)alloc((size_t)N_NODES * 4);
    f16* Bt1 = (f16*)alloc((size_t)HIDDEN * 2 * IN_DIM * 2);
    f16* Bt2 = (f16*)alloc((size_t)HIDDEN * 2 * HIDDEN * 2);
    f16* Bt3 = (f16*)alloc((size_t)HIDDEN * 2 * HIDDEN * 2);
    f16* GA  = (f16*)alloc((size_t)M_PAD * HIDDEN * 2);   // GEMM A operand
    f16* F   = (f16*)alloc((size_t)M_PAD * HIDDEN * 2);   // layer output

    if (used > ws_size) return;  // fail cleanly rather than OOB

    hipMemsetAsync(cnt, 0, (size_t)N_NODES * 4, stream);
    hipMemsetAsync(cursor, 0, (size_t)N_NODES * 4, stream);

    count_dst_kernel<<<(N_EDGES + 255) / 256, 256, 0, stream>>>(dstp, cnt);
    dis_kernel<<<(N_NODES + 255) / 256, 256, 0, stream>>>(cnt, dis);
    scan1_kernel<<<SCAN_B, 256, 0, stream>>>(cnt, bsum);
    scan2_kernel<<<1, 256, 0, stream>>>(bsum, boff);
    scan3_kernel<<<SCAN_B, 256, 0, stream>>>(cnt, boff, off);
    fill_csr_kernel<<<(N_EDGES + 255) / 256, 256, 0, stream>>>(srcp, dstp, off, cursor, dis,
                                                               csr_src, csr_w);

    convw_kernel<<<(IN_DIM * HIDDEN + 255) / 256, 256, 0, stream>>>(W1, Bt1, IN_DIM);
    convw_kernel<<<(HIDDEN * HIDDEN + 255) / 256, 256, 0, stream>>>(W2, Bt2, HIDDEN);
    convw_kernel<<<(HIDDEN * HIDDEN + 255) / 256, 256, 0, stream>>>(W3, Bt3, HIDDEN);

    int gemm_blocks = (HIDDEN / 128) * (M_PAD / 128);   // 1564, 1D for XCD swizzle

    // layer 1: GA = agg(x);  F = tanh(GA @ W1' + b1)
    agg1_kernel<<<(N_NODES + 7) / 8, 256, 0, stream>>>(x, dis, off, csr_src, csr_w, GA);
    gemm_mfma_kernel<<<gemm_blocks, 256, 0, stream>>>(GA, Bt1, b1, F, N_NODES, IN_DIM);
    // layer 2
    agg_f16_kernel<<<(N_NODES + 3) / 4, 256, 0, stream>>>(F, dis, off, csr_src, csr_w, GA);
    gemm_mfma_kernel<<<gemm_blocks, 256, 0, stream>>>(GA, Bt2, b2, F, N_NODES, HIDDEN);
    // layer 3
    agg_f16_kernel<<<(N_NODES + 3) / 4, 256, 0, stream>>>(F, dis, off, csr_src, csr_w, GA);
    gemm_mfma_kernel<<<gemm_blocks, 256, 0, stream>>>(GA, Bt3, b3, F, N_NODES, HIDDEN);
    // final scoring
    edge_score_kernel<<<(N_TRAIN + 3) / 4, 256, 0, stream>>>(F, srcp, dstp, te, fc2W, fc2b,
                                                             (float*)d_out);
}

// Round 12
// 357.751 us; speedup vs baseline: 1.7079x; 1.1675x over previous
//
#include <hip/hip_runtime.h>
#include <math.h>

#define N_NODES 50000
#define N_EDGES 400000
#define N_TRAIN 50000
#define IN_DIM  128
#define HIDDEN  512
#define M_PAD   50048   // 391 * 128
#define SCAN_B  196     // 196 * 256 = 50176 >= N_NODES

typedef _Float16 f16;
typedef __attribute__((ext_vector_type(8))) _Float16 f16x8;
typedef __attribute__((ext_vector_type(4))) _Float16 f16x4;
typedef __attribute__((ext_vector_type(4))) float f32x4;

// ---------------- graph preprocessing ----------------

__global__ void count_dst_kernel(const int* __restrict__ dst, int* __restrict__ cnt) {
    int i = blockIdx.x * blockDim.x + threadIdx.x;
    if (i < N_EDGES) atomicAdd(&cnt[dst[i]], 1);
}

__global__ void dis_kernel(const int* __restrict__ cnt, float* __restrict__ dis) {
    int v = blockIdx.x * blockDim.x + threadIdx.x;
    if (v < N_NODES) dis[v] = rsqrtf(1.0f + (float)cnt[v]);  // +1 self-loop
}

// ---- hierarchical scan ----
__global__ void scan1_kernel(const int* __restrict__ cnt, int* __restrict__ bsum) {
    __shared__ int red[256];
    int t = threadIdx.x, i = blockIdx.x * 256 + t;
    red[t] = (i < N_NODES) ? cnt[i] : 0;
    __syncthreads();
    for (int o = 128; o > 0; o >>= 1) {
        if (t < o) red[t] += red[t + o];
        __syncthreads();
    }
    if (t == 0) bsum[blockIdx.x] = red[0];
}

__global__ void scan2_kernel(const int* __restrict__ bsum, int* __restrict__ boff) {
    __shared__ int part[256];
    int t = threadIdx.x;
    int v = (t < SCAN_B) ? bsum[t] : 0;
    part[t] = v;
    __syncthreads();
    for (int o = 1; o < 256; o <<= 1) {
        int u = (t >= o) ? part[t - o] : 0;
        __syncthreads();
        part[t] += u;
        __syncthreads();
    }
    if (t < SCAN_B) boff[t] = part[t] - v;   // exclusive
}

__global__ void scan3_kernel(const int* __restrict__ cnt, const int* __restrict__ boff,
                             int* __restrict__ off) {
    __shared__ int part[256];
    int t = threadIdx.x, i = blockIdx.x * 256 + t;
    int v = (i < N_NODES) ? cnt[i] : 0;
    part[t] = v;
    __syncthreads();
    for (int o = 1; o < 256; o <<= 1) {
        int u = (t >= o) ? part[t - o] : 0;
        __syncthreads();
        part[t] += u;
        __syncthreads();
    }
    int excl = part[t] - v;
    int base = boff[blockIdx.x];
    if (i < N_NODES) off[i] = base + excl;
    if (i == N_NODES - 1) off[N_NODES] = base + excl + v;   // total
}

// CSR fill; also precompute per-edge src-side norm weight.
__global__ void fill_csr_kernel(const int* __restrict__ src, const int* __restrict__ dst,
                                const int* __restrict__ off, int* __restrict__ cursor,
                                const float* __restrict__ dis,
                                int* __restrict__ csr_src, float* __restrict__ csr_w) {
    int i = blockIdx.x * blockDim.x + threadIdx.x;
    if (i < N_EDGES) {
        int d = dst[i], s = src[i];
        int p = atomicAdd(&cursor[d], 1);
        int idx = off[d] + p;
        csr_src[idx] = s;
        csr_w[idx] = dis[s];
    }
}

// ---- weight conversion: W[K][512] -> Bt[512][K] single f16 (lo-term dropped: error
// model says +~1.4e-4/layer pre-activation, total ~5-9e-4 vs 2.9e-3 threshold) ----
__global__ void convw_kernel(const float* __restrict__ W, f16* __restrict__ Bt, int K) {
    int idx = blockIdx.x * blockDim.x + threadIdx.x;
    if (idx >= K * HIDDEN) return;
    int k = idx / HIDDEN, n = idx % HIDDEN;
    Bt[(size_t)n * K + k] = (f16)W[(size_t)k * HIDDEN + n];
}

// ------------- layer-1 aggregation: f32 x (D=128) -> fp16, 2-way unrolled -------------
__global__ void agg1_kernel(const float* __restrict__ x, const float* __restrict__ dis,
                            const int* __restrict__ off, const int* __restrict__ csr_src,
                            const float* __restrict__ csr_w, f16* __restrict__ A) {
    const int TPN = 32;   // 128/4
    int node = blockIdx.x * 8 + threadIdx.x / TPN;
    if (node >= N_NODES) return;
    int t = threadIdx.x % TPN;
    float dv = dis[node];
    float w0 = dv * dv;
    float4 a = ((const float4*)(x + (size_t)node * IN_DIM))[t];
    float4 acc = make_float4(a.x * w0, a.y * w0, a.z * w0, a.w * w0);
    float4 acc1 = make_float4(0.f, 0.f, 0.f, 0.f);
    int s0 = off[node], s1 = off[node + 1];
    int k = s0;
    for (; k + 2 <= s1; k += 2) {
        int sa = csr_src[k], sb = csr_src[k + 1];
        float wa = csr_w[k] * dv, wb = csr_w[k + 1] * dv;
        float4 ba = ((const float4*)(x + (size_t)sa * IN_DIM))[t];
        float4 bb = ((const float4*)(x + (size_t)sb * IN_DIM))[t];
        acc.x = fmaf(wa, ba.x, acc.x);   acc.y = fmaf(wa, ba.y, acc.y);
        acc.z = fmaf(wa, ba.z, acc.z);   acc.w = fmaf(wa, ba.w, acc.w);
        acc1.x = fmaf(wb, bb.x, acc1.x); acc1.y = fmaf(wb, bb.y, acc1.y);
        acc1.z = fmaf(wb, bb.z, acc1.z); acc1.w = fmaf(wb, bb.w, acc1.w);
    }
    if (k < s1) {
        int sa = csr_src[k];
        float wa = csr_w[k] * dv;
        float4 ba = ((const float4*)(x + (size_t)sa * IN_DIM))[t];
        acc.x = fmaf(wa, ba.x, acc.x); acc.y = fmaf(wa, ba.y, acc.y);
        acc.z = fmaf(wa, ba.z, acc.z); acc.w = fmaf(wa, ba.w, acc.w);
    }
    f16x4 o;
    o.x = (f16)(acc.x + acc1.x); o.y = (f16)(acc.y + acc1.y);
    o.z = (f16)(acc.z + acc1.z); o.w = (f16)(acc.w + acc1.w);
    *(f16x4*)&A[(size_t)node * IN_DIM + t * 4] = o;
}

// ------- aggregation: fp16 h (512) -> fp16, cascaded 8/4/2/1 unroll -------
__global__ void agg_f16_kernel(const f16* __restrict__ h, const float* __restrict__ dis,
                               const int* __restrict__ off, const int* __restrict__ csr_src,
                               const float* __restrict__ csr_w, f16* __restrict__ A) {
    const int TPN = 64;   // 512/8, one wave per node
    int node = blockIdx.x * 4 + threadIdx.x / TPN;
    if (node >= N_NODES) return;
    int t = threadIdx.x % TPN;
    float dv = dis[node];
    float w0 = dv * dv;
    f16x8 a = *(const f16x8*)&h[(size_t)node * HIDDEN + t * 8];
    float acc0[8], acc1[8];
    #pragma unroll
    for (int j = 0; j < 8; j++) { acc0[j] = w0 * (float)a[j]; acc1[j] = 0.f; }
    int s0 = off[node], s1 = off[node + 1];
    int k = s0;
    for (; k + 8 <= s1; k += 8) {      // eight independent row gathers in flight
        f16x8 b[8];
        float w[8];
        #pragma unroll
        for (int u = 0; u < 8; u++) {
            int su = csr_src[k + u];
            w[u] = csr_w[k + u] * dv;
            b[u] = *(const f16x8*)&h[(size_t)su * HIDDEN + t * 8];
        }
        #pragma unroll
        for (int j = 0; j < 8; j++) {
            acc0[j] = fmaf(w[0], (float)b[0][j], acc0[j]);
            acc1[j] = fmaf(w[1], (float)b[1][j], acc1[j]);
            acc0[j] = fmaf(w[2], (float)b[2][j], acc0[j]);
            acc1[j] = fmaf(w[3], (float)b[3][j], acc1[j]);
            acc0[j] = fmaf(w[4], (float)b[4][j], acc0[j]);
            acc1[j] = fmaf(w[5], (float)b[5][j], acc1[j]);
            acc0[j] = fmaf(w[6], (float)b[6][j], acc0[j]);
            acc1[j] = fmaf(w[7], (float)b[7][j], acc1[j]);
        }
    }
    if (k + 4 <= s1) {
        f16x8 b[4];
        float w[4];
        #pragma unroll
        for (int u = 0; u < 4; u++) {
            int su = csr_src[k + u];
            w[u] = csr_w[k + u] * dv;
            b[u] = *(const f16x8*)&h[(size_t)su * HIDDEN + t * 8];
        }
        #pragma unroll
        for (int j = 0; j < 8; j++) {
            acc0[j] = fmaf(w[0], (float)b[0][j], acc0[j]);
            acc1[j] = fmaf(w[1], (float)b[1][j], acc1[j]);
            acc0[j] = fmaf(w[2], (float)b[2][j], acc0[j]);
            acc1[j] = fmaf(w[3], (float)b[3][j], acc1[j]);
        }
        k += 4;
    }
    if (k + 2 <= s1) {
        int sa = csr_src[k], sb = csr_src[k + 1];
        float wa = csr_w[k] * dv, wb = csr_w[k + 1] * dv;
        f16x8 ba = *(const f16x8*)&h[(size_t)sa * HIDDEN + t * 8];
        f16x8 bb = *(const f16x8*)&h[(size_t)sb * HIDDEN + t * 8];
        #pragma unroll
        for (int j = 0; j < 8; j++) {
            acc0[j] = fmaf(wa, (float)ba[j], acc0[j]);
            acc1[j] = fmaf(wb, (float)bb[j], acc1[j]);
        }
        k += 2;
    }
    if (k < s1) {
        int sa = csr_src[k];
        float wa = csr_w[k] * dv;
        f16x8 ba = *(const f16x8*)&h[(size_t)sa * HIDDEN + t * 8];
        #pragma unroll
        for (int j = 0; j < 8; j++) acc0[j] = fmaf(wa, (float)ba[j], acc0[j]);
    }
    f16x8 o;
    #pragma unroll
    for (int j = 0; j < 8; j++) o[j] = (f16)(acc0[j] + acc1[j]);
    *(f16x8*)&A[(size_t)node * HIDDEN + t * 8] = o;
}

// ------- MFMA fp16 GEMM, single-f16 weights: 128x128 tile, 4 waves, ~35KB LDS, 4 blk/CU ----
// C[M][512] = tanh(A @ B + bias).  BK=64; 32 MFMA/wave/step; staging 8x16B/thread/step.
// XOR-swizzle per rule #21 (linear LDS dest + inverse-swizzled global src + swizzled read).
// Epilogue: acc -> LDS (stride 136 f16, 16B-aligned slots) -> coalesced f16x8 stores.
__global__ __launch_bounds__(256, 4) void gemm_mfma_kernel(
    const f16* __restrict__ A, const f16* __restrict__ Bt, const float* __restrict__ bias,
    f16* __restrict__ C, int M, int Kb) {
    __shared__ f16 smem[17408];          // K-loop: As[8192]|Bs[8192]=32KB; epilogue: 128x136
    f16* As = smem;
    f16* Bs = smem + 8192;
    int tid = threadIdx.x;
    int lane = tid & 63, wv = tid >> 6;
    int wr = wv >> 1, wc = wv & 1;       // 2x2 waves, 64x64 output each

    // bijective XCD swizzle (m204); grid 1564 = 4 * 391
    int nwg = gridDim.x;
    int q = nwg >> 3, r = nwg & 7;
    int xcd = blockIdx.x & 7, pos = blockIdx.x >> 3;
    int wgid = (xcd < r ? xcd * (q + 1) : r * (q + 1) + (xcd - r) * q) + pos;
    int j0 = (wgid & 3) * 128;           // 4 col tiles
    int i0 = (wgid >> 2) * 128;          // 391 row tiles

    int l15 = lane & 15, l4 = lane >> 4;

    f32x4 acc[4][4];
    #pragma unroll
    for (int m = 0; m < 4; m++)
        #pragma unroll
        for (int n = 0; n < 4; n++)
            acc[m][n] = (f32x4){0.f, 0.f, 0.f, 0.f};

    const int nt = Kb / 64;
    for (int t = 0; t < nt; t++) {
        int k0 = t * 64;
        if (t) __syncthreads();          // previous step's readers done -> LDS reusable
        #pragma unroll
        for (int i = 0; i < 4; i++) {    // A: 128x64 = 1024 slots (4 loads/thread)
            int s = i * 256 + tid;
            int row = s >> 3, c8 = s & 7;
            int c8s = c8 ^ (row & 7);    // inverse-swizzled source column
            const f16* gp = A + (size_t)(i0 + row) * Kb + k0 + c8s * 8;
            f16* lp = &As[(i * 256 + wv * 64) * 8];   // wave-uniform base
            __builtin_amdgcn_global_load_lds(
                (const __attribute__((address_space(1))) void*)gp,
                (__attribute__((address_space(3))) void*)lp, 16, 0, 0);
        }
        #pragma unroll
        for (int i = 0; i < 4; i++) {    // B: 128x64 = 1024 slots (4 loads/thread)
            int s = i * 256 + tid;
            int row = s >> 3, c8 = s & 7;
            int c8s = c8 ^ (row & 7);
            const f16* gp = Bt + (size_t)(j0 + row) * Kb + k0 + c8s * 8;
            f16* lp = &Bs[(i * 256 + wv * 64) * 8];
            __builtin_amdgcn_global_load_lds(
                (const __attribute__((address_space(1))) void*)gp,
                (__attribute__((address_space(3))) void*)lp, 16, 0, 0);
        }
        __syncthreads();                 // drain vmcnt -> tiles resident

        f16x8 af[4][2], bfr[4][2];
        #pragma unroll
        for (int m = 0; m < 4; m++) {
            int row = wr * 64 + m * 16 + l15;
            #pragma unroll
            for (int kk = 0; kk < 2; kk++) {
                int slot = (kk * 4 + l4) ^ (row & 7);
                af[m][kk] = *(const f16x8*)&As[row * 64 + slot * 8];
            }
        }
        #pragma unroll
        for (int n = 0; n < 4; n++) {
            int brow = wc * 64 + n * 16 + l15;
            #pragma unroll
            for (int kk = 0; kk < 2; kk++) {
                int slot = (kk * 4 + l4) ^ (brow & 7);
                bfr[n][kk] = *(const f16x8*)&Bs[brow * 64 + slot * 8];
            }
        }
        #pragma unroll
        for (int m = 0; m < 4; m++)
            #pragma unroll
            for (int n = 0; n < 4; n++)
                #pragma unroll
                for (int kk = 0; kk < 2; kk++)
                    acc[m][n] = __builtin_amdgcn_mfma_f32_16x16x32_f16(
                        af[m][kk], bfr[n][kk], acc[m][n], 0, 0, 0);
    }

    // ---- epilogue: acc -> LDS (stride 136 = 16B-aligned slots) -> coalesced stores ----
    __syncthreads();                     // all waves done reading K-loop LDS
    #pragma unroll
    for (int m = 0; m < 4; m++) {
        #pragma unroll
        for (int n = 0; n < 4; n++) {
            int lcol = wc * 64 + n * 16 + l15;
            float bc = bias[j0 + lcol];
            #pragma unroll
            for (int rr = 0; rr < 4; rr++) {
                int lrow = wr * 64 + m * 16 + l4 * 4 + rr;
                smem[lrow * 136 + lcol] = (f16)tanhf(acc[m][n][rr] + bc);
            }
        }
    }
    __syncthreads();
    #pragma unroll
    for (int j = 0; j < 8; j++) {        // 128 rows x 16 chunks of 16B
        int qq = j * 256 + tid;
        int row = qq >> 4, c8 = qq & 15;
        int grow = i0 + row;
        if (grow < M)
            *(f16x8*)&C[(size_t)grow * HIDDEN + j0 + c8 * 8] =
                *(const f16x8*)&smem[row * 136 + c8 * 8];
    }
}

// ---------------- final edge scoring (fp16 input) ----------------
__global__ void edge_score_kernel(const f16* __restrict__ h,
                                  const int* __restrict__ src, const int* __restrict__ dst,
                                  const int* __restrict__ te, const float* __restrict__ wgt,
                                  const float* __restrict__ fc2b, float* __restrict__ out) {
    int wid = threadIdx.x / 64;
    int lane = threadIdx.x % 64;
    int e = blockIdx.x * 4 + wid;
    if (e >= N_TRAIN) return;
    int id = te[e];
    int a = src[id], b = dst[id];
    f16x8 ha = *(const f16x8*)&h[(size_t)a * HIDDEN + lane * 8];
    f16x8 hb = *(const f16x8*)&h[(size_t)b * HIDDEN + lane * 8];
    float4 w0 = *(const float4*)&wgt[lane * 8];
    float4 w1 = *(const float4*)&wgt[lane * 8 + 4];
    float acc = 0.f;
    acc += (float)ha[0] * (float)hb[0] * w0.x;
    acc += (float)ha[1] * (float)hb[1] * w0.y;
    acc += (float)ha[2] * (float)hb[2] * w0.z;
    acc += (float)ha[3] * (float)hb[3] * w0.w;
    acc += (float)ha[4] * (float)hb[4] * w1.x;
    acc += (float)ha[5] * (float)hb[5] * w1.y;
    acc += (float)ha[6] * (float)hb[6] * w1.z;
    acc += (float)ha[7] * (float)hb[7] * w1.w;
    #pragma unroll
    for (int o = 32; o > 0; o >>= 1) acc += __shfl_down(acc, o);
    if (lane == 0) out[e] = acc + fc2b[0];
}

// ---------------- launch ----------------

extern "C" void kernel_launch(void* const* d_in, const int* in_sizes, int n_in,
                              void* d_out, int out_size, void* d_ws, size_t ws_size,
                              hipStream_t stream) {
    const float* x    = (const float*)d_in[0];
    const int*   eidx = (const int*)d_in[1];
    const int*   te   = (const int*)d_in[2];
    const float* W1   = (const float*)d_in[3];
    const float* b1   = (const float*)d_in[4];
    const float* W2   = (const float*)d_in[5];
    const float* b2   = (const float*)d_in[6];
    const float* W3   = (const float*)d_in[7];
    const float* b3   = (const float*)d_in[8];
    const float* fc2W = (const float*)d_in[9];
    const float* fc2b = (const float*)d_in[10];
    const int* srcp = eidx;
    const int* dstp = eidx + N_EDGES;

    char* ws = (char*)d_ws;
    size_t used = 0;
    auto alloc = [&](size_t bytes) {
        void* p = ws + used;
        used += (bytes + 255) / 256 * 256;
        return p;
    };
    int*   cnt     = (int*)alloc((size_t)N_NODES * 4);
    int*   off     = (int*)alloc((size_t)(N_NODES + 1) * 4);
    int*   cursor  = (int*)alloc((size_t)N_NODES * 4);
    int*   bsum    = (int*)alloc((size_t)SCAN_B * 4);
    int*   boff    = (int*)alloc((size_t)SCAN_B * 4);
    int*   csr_src = (int*)alloc((size_t)N_EDGES * 4);
    float* csr_w   = (float*)alloc((size_t)N_EDGES * 4);
    float* dis     = (float*)alloc((size_t)N_NODES * 4);
    f16* Bt1 = (f16*)alloc((size_t)HIDDEN * IN_DIM * 2);
    f16* Bt2 = (f16*)alloc((size_t)HIDDEN * HIDDEN * 2);
    f16* Bt3 = (f16*)alloc((size_t)HIDDEN * HIDDEN * 2);
    f16* GA  = (f16*)alloc((size_t)M_PAD * HIDDEN * 2);   // GEMM A operand
    f16* F   = (f16*)alloc((size_t)M_PAD * HIDDEN * 2);   // layer output

    if (used > ws_size) return;  // fail cleanly rather than OOB

    hipMemsetAsync(cnt, 0, (size_t)N_NODES * 4, stream);
    hipMemsetAsync(cursor, 0, (size_t)N_NODES * 4, stream);

    count_dst_kernel<<<(N_EDGES + 255) / 256, 256, 0, stream>>>(dstp, cnt);
    dis_kernel<<<(N_NODES + 255) / 256, 256, 0, stream>>>(cnt, dis);
    scan1_kernel<<<SCAN_B, 256, 0, stream>>>(cnt, bsum);
    scan2_kernel<<<1, 256, 0, stream>>>(bsum, boff);
    scan3_kernel<<<SCAN_B, 256, 0, stream>>>(cnt, boff, off);
    fill_csr_kernel<<<(N_EDGES + 255) / 256, 256, 0, stream>>>(srcp, dstp, off, cursor, dis,
                                                               csr_src, csr_w);

    convw_kernel<<<(IN_DIM * HIDDEN + 255) / 256, 256, 0, stream>>>(W1, Bt1, IN_DIM);
    convw_kernel<<<(HIDDEN * HIDDEN + 255) / 256, 256, 0, stream>>>(W2, Bt2, HIDDEN);
    convw_kernel<<<(HIDDEN * HIDDEN + 255) / 256, 256, 0, stream>>>(W3, Bt3, HIDDEN);

    int gemm_blocks = (HIDDEN / 128) * (M_PAD / 128);   // 1564, 1D for XCD swizzle

    // layer 1: GA = agg(x);  F = tanh(GA @ W1 + b1)
    agg1_kernel<<<(N_NODES + 7) / 8, 256, 0, stream>>>(x, dis, off, csr_src, csr_w, GA);
    gemm_mfma_kernel<<<gemm_blocks, 256, 0, stream>>>(GA, Bt1, b1, F, N_NODES, IN_DIM);
    // layer 2
    agg_f16_kernel<<<(N_NODES + 3) / 4, 256, 0, stream>>>(F, dis, off, csr_src, csr_w, GA);
    gemm_mfma_kernel<<<gemm_blocks, 256, 0, stream>>>(GA, Bt2, b2, F, N_NODES, HIDDEN);
    // layer 3
    agg_f16_kernel<<<(N_NODES + 3) / 4, 256, 0, stream>>>(F, dis, off, csr_src, csr_w, GA);
    gemm_mfma_kernel<<<gemm_blocks, 256, 0, stream>>>(GA, Bt3, b3, F, N_NODES, HIDDEN);
    // final scoring
    edge_score_kernel<<<(N_TRAIN + 3) / 4, 256, 0, stream>>>(F, srcp, dstp, te, fc2W, fc2b,
                                                             (float*)d_out);
}